// Round 1
// baseline (4992.739 us; speedup 1.0000x reference)
//
#include <hip/hip_runtime.h>

using short8 = __attribute__((ext_vector_type(8))) short;
using f32x4  = __attribute__((ext_vector_type(4))) float;
typedef unsigned short u16;
typedef unsigned int   u32;
typedef unsigned long long u64;

constexpr int Bn = 256;   // batch
constexpr int Tn = 200;   // time steps
constexpr int Dn = 512;   // hidden size

__device__ __forceinline__ u16 f2bf(float x) {
  union { float f; unsigned u; } v; v.f = x;
  unsigned r = v.u + 0x7FFFu + ((v.u >> 16) & 1u);  // RNE
  return (u16)(r >> 16);
}
__device__ __forceinline__ float sigm(float x) { return 1.0f / (1.0f + __expf(-x)); }
__device__ __forceinline__ float tanhe(float x) { return 1.0f - 2.0f / (__expf(2.0f * x) + 1.0f); }

// ---------- prep: x f32 [B][T][D] -> xf fragment-major bf16 [mtile4][t200][rf4][kkd16][lane64][8] ----------
__global__ void cvt_x_frag(const float* __restrict__ x, u16* __restrict__ xf) {
  int i = blockIdx.x * 256 + threadIdx.x;          // exactly 3,276,800 lane-tasks
  int lane = i & 63;
  int kkd  = (i >> 6) & 15;
  int rf   = (i >> 10) & 3;
  int mt_t = i >> 12;                              // mtile*200 + t
  int t = mt_t % 200, mtile = mt_t / 200;
  int row = mtile * 64 + rf * 16 + (lane & 15);
  int k0  = kkd * 32 + (lane >> 4) * 8;
  const float* s = x + ((size_t)row * Tn + t) * Dn + k0;
  float4 v0 = *reinterpret_cast<const float4*>(s);
  float4 v1 = *reinterpret_cast<const float4*>(s + 4);
  short8 r;
  r[0]=(short)f2bf(v0.x); r[1]=(short)f2bf(v0.y); r[2]=(short)f2bf(v0.z); r[3]=(short)f2bf(v0.w);
  r[4]=(short)f2bf(v1.x); r[5]=(short)f2bf(v1.y); r[6]=(short)f2bf(v1.z); r[7]=(short)f2bf(v1.w);
  reinterpret_cast<short8*>(xf)[i] = r;
}

// ---------- prep: W [1024][2048] f32 -> Wf fragment-major bf16 [role2][dsl32][g4][kk32][lane64][8] ----------
__global__ void cvt_w_frag(const float* __restrict__ W0, const float* __restrict__ W1,
                           u16* __restrict__ Wf) {
  __shared__ u16 T[64][65];                        // [k][n] tile, padded
  int b = blockIdx.x;                              // 1024 blocks: role(2) x kt(16) x nt(32)
  int nt = b & 31, kt = (b >> 5) & 15, role = b >> 9;
  const float* W = role ? W1 : W0;
  int t = threadIdx.x;
  int k0 = kt * 64, n0 = nt * 64;
  int kr = t >> 6, nl = t & 63;
#pragma unroll
  for (int r = 0; r < 16; ++r) {
    int k = r * 4 + kr;
    T[k][nl] = f2bf(W[(size_t)(k0 + k) * 2048 + n0 + nl]);   // coalesced over n
  }
  __syncthreads();
  int g = n0 >> 9;
  int dslBase = (n0 & 511) >> 4;
  int kkBase  = k0 >> 5;
  int lane = t & 63, grp = t >> 6;
  int lr = lane & 15, lk = lane >> 4;
#pragma unroll
  for (int c = grp; c < 8; c += 4) {
    int dslL = c & 3, kkL = c >> 2;
    int dsl = dslBase + dslL, kk = kkBase + kkL;
    short8 v;
#pragma unroll
    for (int e = 0; e < 8; ++e)
      v[e] = (short)T[kkL * 32 + lk * 8 + e][dslL * 16 + lr];
    *reinterpret_cast<short8*>(Wf + ((((size_t)(role * 32 + dsl) * 4 + g) * 32 + kk) * 64 + lane) * 8) = v;
  }
}

#define MFMA16 __builtin_amdgcn_mfma_f32_16x16x32_bf16
#define GLOAD_LDS(g, l) __builtin_amdgcn_global_load_lds(                    \
    (const __attribute__((address_space(1))) void*)(g),                      \
    (__attribute__((address_space(3))) void*)(l), 16, 0, 0)

#define LDA(kk) (*reinterpret_cast<const short8*>(                           \
    (kk) < 16 ? (Alo + (size_t)(kk) * 1024) : (Ahi + (size_t)((kk) - 16) * 1024)))

// ---------- persistent cooperative kernel: entire 200-step scan in ONE launch ----------
// 256 blocks x 256 threads, 1 block/CU. role = blk&1, mtile = (blk>>1)&3, dsl = blk>>3.
// W slice (128 KB) staged into LDS ONCE; c-state and copy-through h held in registers.
// Per-iteration sync: per-mtile 64-block monotonic-counter barrier (agent scope),
// release-RMW flushes XCD L2 -> LLC; acquire fence invalidates so fresh h is read.
// Skewed schedule as before: iter p = layer0 step p (role0) + layer1 step p-1 (role1).
extern "C" __global__ void __launch_bounds__(256, 1)
rnn_persist(const u16* __restrict__ xf, const u16* __restrict__ Wf,
            const float* __restrict__ b0, const float* __restrict__ b1,
            const int* __restrict__ seq,
            u16* __restrict__ hf0, u16* __restrict__ hf1,
            u32* __restrict__ bar, float* __restrict__ out) {
  extern __shared__ __align__(16) char smem[];
  const int blk = blockIdx.x;
  const int role = blk & 1;
  const int mtile = (blk >> 1) & 3;
  const int dsl = blk >> 3;
  const int tid = threadIdx.x;
  const int rf = tid >> 6, lane = tid & 63;

  // ---- one-time W staging: 32 direct global->LDS 16B ops per thread ----
  {
    const char* gsrc = reinterpret_cast<const char*>(Wf)
                     + (size_t)(role * 32 + dsl) * 131072 + tid * 16;
    char* lds = smem + tid * 16;
#pragma unroll
    for (int i = 0; i < 32; ++i)
      GLOAD_LDS(gsrc + i * 4096, lds + i * 4096);
  }

  const char* xfb    = reinterpret_cast<const char*>(xf);
  const char* h0base = reinterpret_cast<const char*>(hf0);
  const char* h1base = reinterpret_cast<const char*>(hf1);
  const int aoff = rf * 16384 + lane * 16;
  const char* WL = smem + lane * 16;               // + g*32768 + kk*1024 (ds_read_b128)

  const int d0 = dsl * 16 + (lane & 15);
  const float* bias = role ? b1 : b0;
  const float bg0 = bias[d0], bg1 = bias[512 + d0], bg2 = bias[1024 + d0], bg3 = bias[1536 + d0];
  const int rowB = mtile * 64 + rf * 16 + (lane >> 4) * 4;
  int sl[4];
#pragma unroll
  for (int e = 0; e < 4; ++e) sl[e] = seq[rowB + e];

  // fragment-layout u16 offset of this thread's (rowB+e, d0) values in h buffers
  const int kkd = dsl >> 1;
  const int lane_t_base = ((((dsl & 1) << 1) | ((lane & 15) >> 3)) << 4) + (lane >> 4) * 4;
  const size_t hoff0 = (size_t)mtile * 32768 + (size_t)(rf * 16 + kkd) * 512
                     + (size_t)lane_t_base * 8 + (lane & 7);

  u16* hfSelf = role ? hf1 : hf0;
  u16* stg = reinterpret_cast<u16*>(smem + 131072);
  const int uu = tid & 63;
  const size_t o8 = (size_t)((mtile * 4 + rf) * 16 + kkd) * 128
                  + ((dsl & 1) * 32 + (uu >> 1)) * 2 + (uu & 1);
  u32* mycnt = bar + mtile * 64;                   // 256B-spaced per-mtile counters

  float creg[4]  = {0.f, 0.f, 0.f, 0.f};           // c-state lives in registers now
  float hkeep[4] = {0.f, 0.f, 0.f, 0.f};           // copy-through h lives in registers now

  short8 ca0, ca1, ca2, ca3, na0, na1, na2, na3;
  if (role == 0) {                                 // prefetch x fragments for p=0
    const char* An = xfb + ((size_t)mtile * Tn + 0) * 65536 + aoff;
    ca0 = *reinterpret_cast<const short8*>(An);
    ca1 = *reinterpret_cast<const short8*>(An + 1024);
    ca2 = *reinterpret_cast<const short8*>(An + 2048);
    ca3 = *reinterpret_cast<const short8*>(An + 3072);
  }

  __syncthreads();                                 // W resident in LDS from here on

#pragma unroll 1
  for (int p = 0; p <= Tn; ++p) {
    const bool act = role ? (p >= 1) : (p < Tn);
    const int Rp = (p & 1) ^ 1, Wp = p & 1;
    if (act) {
      const int tcur = role ? (p - 1) : p;
      const size_t hRp = (size_t)Rp * 262144 + (size_t)mtile * 65536;
      const char* Alo;   // K 0..511
      const char* Ahi;   // K 512..1023
      if (role == 0) {
        Alo = xfb + ((size_t)mtile * Tn + p) * 65536 + aoff;
        Ahi = h0base + hRp + aoff;
      } else {
        Alo = h0base + hRp + aoff;
        Ahi = h1base + hRp + aoff;
      }
      if (role) { ca0 = LDA(0); ca1 = LDA(1); ca2 = LDA(2); ca3 = LDA(3); }
      u16 h0nraw[4];
      if (role) {                                  // residual h0n read (fresh after barrier)
        const u16* hr = reinterpret_cast<const u16*>(h0base) + (size_t)Rp * 131072;
#pragma unroll
        for (int e = 0; e < 4; ++e) h0nraw[e] = hr[hoff0 + e * 8];
      }

      f32x4 ac0 = {0.f,0.f,0.f,0.f}, ac1 = {0.f,0.f,0.f,0.f};
      f32x4 ac2 = {0.f,0.f,0.f,0.f}, ac3 = {0.f,0.f,0.f,0.f};
#pragma unroll
      for (int c = 0; c < 8; ++c) {                // fully unrolled: all indices static
        const int k0 = c * 4;
        if (c < 7) {
          na0 = LDA(k0 + 4); na1 = LDA(k0 + 5); na2 = LDA(k0 + 6); na3 = LDA(k0 + 7);
        }
#pragma unroll
        for (int j = 0; j < 4; ++j) {
          const int kk = k0 + j;
          short8 a = (j == 0) ? ca0 : (j == 1) ? ca1 : (j == 2) ? ca2 : ca3;
          short8 w0 = *reinterpret_cast<const short8*>(WL + kk * 1024);
          short8 w1 = *reinterpret_cast<const short8*>(WL + 32768 + kk * 1024);
          short8 w2 = *reinterpret_cast<const short8*>(WL + 65536 + kk * 1024);
          short8 w3 = *reinterpret_cast<const short8*>(WL + 98304 + kk * 1024);
          ac0 = MFMA16(a, w0, ac0, 0, 0, 0);
          ac1 = MFMA16(a, w1, ac1, 0, 0, 0);
          ac2 = MFMA16(a, w2, ac2, 0, 0, 0);
          ac3 = MFMA16(a, w3, ac3, 0, 0, 0);
        }
        ca0 = na0; ca1 = na1; ca2 = na2; ca3 = na3;
      }

      // epilogue: gates (i,j,f,o), state update from registers, copy-through from registers
#pragma unroll
      for (int e = 0; e < 4; ++e) {
        float zi = ac0[e] + bg0, zj = ac1[e] + bg1, zf = ac2[e] + bg2, zo = ac3[e] + bg3;
        float cprev = creg[e];
        float cn = cprev * sigm(zf + 1.0f) + sigm(zi) * tanhe(zj);
        float hn = tanhe(cn) * sigm(zo);
        bool valid = tcur < sl[e];
        float hk = valid ? hn : hkeep[e];
        creg[e] = valid ? cn : cprev;
        hkeep[e] = hk;
        stg[rf * 256 + (((lane & 15) >> 3) * 16 + (lane >> 4) * 4 + e) * 8 + (lane & 7)] = f2bf(hk);
        if (role) {
          union { float f; u32 u; } hv; hv.u = ((u32)h0nraw[e]) << 16;       // h0n (bf16)
          out[((size_t)(rowB + e) * Tn + tcur) * Dn + d0] = valid ? (hn + hv.f) : 0.0f;
        }
      }
      __syncthreads();
      {  // cooperative coalesced store of the 2KB h slice into the write parity
        u64 v = reinterpret_cast<const u64*>(stg)[tid];
        u64* hw8 = reinterpret_cast<u64*>(hfSelf + (size_t)Wp * 131072);
        hw8[o8] = v;
      }
    }

    if (p == Tn) break;                            // nothing reads after the last step

    // role0: prefetch next step's x fragments (h-independent) across the barrier
    if (role == 0 && p + 1 < Tn) {
      const char* An = xfb + ((size_t)mtile * Tn + (p + 1)) * 65536 + aoff;
      ca0 = *reinterpret_cast<const short8*>(An);
      ca1 = *reinterpret_cast<const short8*>(An + 1024);
      ca2 = *reinterpret_cast<const short8*>(An + 2048);
      ca3 = *reinterpret_cast<const short8*>(An + 3072);
    }

    // ---- per-mtile 64-block barrier: monotonic counter, no reset races ----
    __syncthreads();                               // all block writes drained to L2
    if (tid == 0) {
      __hip_atomic_fetch_add(mycnt, 1u, __ATOMIC_RELEASE, __HIP_MEMORY_SCOPE_AGENT);
      const u32 target = 64u * (u32)(p + 1);
      while (__hip_atomic_load(mycnt, __ATOMIC_RELAXED, __HIP_MEMORY_SCOPE_AGENT) < target)
        __builtin_amdgcn_s_sleep(2);
    }
    __syncthreads();
    __threadfence();                               // acquire: invalidate stale L1/L2 lines
  }
}

// ---------- fallback per-step kernel (only used if cooperative launch is rejected) ----------
extern "C" __global__ void __launch_bounds__(256, 1)
rnn_step(const u16* __restrict__ xf, const u16* __restrict__ Wf,
         const float* __restrict__ b0, const float* __restrict__ b1,
         const int* __restrict__ seq,
         u16* __restrict__ hf0, u16* __restrict__ hf1,
         float* __restrict__ cbuf, float* __restrict__ out, int p) {
  extern __shared__ __align__(16) char smem[];
  const int blk = blockIdx.x;
  const int role = blk & 1;
  const int mtile = (blk >> 1) & 3;
  const int dsl = blk >> 3;
  const bool act = role ? (p >= 1) : (p < Tn);
  if (!act) return;

  const int tid = threadIdx.x;
  const int rf = tid >> 6, lane = tid & 63;
  const int Rp = (p & 1) ^ 1, Wp = p & 1;
  const int tcur = role ? (p - 1) : p;

  {
    const char* gsrc = reinterpret_cast<const char*>(Wf)
                     + (size_t)(role * 32 + dsl) * 131072 + tid * 16;
    char* lds = smem + tid * 16;
#pragma unroll
    for (int i = 0; i < 32; ++i)
      GLOAD_LDS(gsrc + i * 4096, lds + i * 4096);
  }

  const char* h0base = reinterpret_cast<const char*>(hf0);
  const char* h1base = reinterpret_cast<const char*>(hf1);
  const size_t hRp = (size_t)Rp * 262144 + (size_t)mtile * 65536;
  const int aoff = rf * 16384 + lane * 16;

  const char* Alo;
  const char* Ahi;
  if (role == 0) {
    Alo = reinterpret_cast<const char*>(xf) + ((size_t)mtile * Tn + p) * 65536 + aoff;
    Ahi = h0base + hRp + aoff;
  } else {
    Alo = h0base + hRp + aoff;
    Ahi = h1base + hRp + aoff;
  }
  const char* WL = smem + lane * 16;

  short8 ca0 = LDA(0), ca1 = LDA(1), ca2 = LDA(2), ca3 = LDA(3);

  const int d0 = dsl * 16 + (lane & 15);
  const float* bias = role ? b1 : b0;
  const float bg0 = bias[d0], bg1 = bias[512 + d0], bg2 = bias[1024 + d0], bg3 = bias[1536 + d0];
  const int rowB = mtile * 64 + rf * 16 + (lane >> 4) * 4;
  int sl[4];
#pragma unroll
  for (int e = 0; e < 4; ++e) sl[e] = seq[rowB + e];

  const int kkd = dsl >> 1;
  const int lane_t_base = ((((dsl & 1) << 1) | ((lane & 15) >> 3)) << 4) + (lane >> 4) * 4;
  const size_t hoff0 = (size_t)mtile * 32768 + (size_t)(rf * 16 + kkd) * 512
                     + (size_t)lane_t_base * 8 + (lane & 7);

  u16 h0nraw[4];
  if (role) {
    const u16* hr = reinterpret_cast<const u16*>(h0base) + (size_t)Rp * 131072;
#pragma unroll
    for (int e = 0; e < 4; ++e) h0nraw[e] = hr[hoff0 + e * 8];
  }
  float* cme = cbuf + ((size_t)blk * 256 + tid) * 4;
  float cpre[4];
#pragma unroll
  for (int e = 0; e < 4; ++e) cpre[e] = cme[e];
  u16* hfSelf = role ? hf1 : hf0;
  const u16* hprev = hfSelf + (size_t)Rp * 131072;
  u16 hp16[4];
#pragma unroll
  for (int e = 0; e < 4; ++e) hp16[e] = hprev[hoff0 + e * 8];

  __syncthreads();

  f32x4 ac0 = {0.f,0.f,0.f,0.f}, ac1 = {0.f,0.f,0.f,0.f};
  f32x4 ac2 = {0.f,0.f,0.f,0.f}, ac3 = {0.f,0.f,0.f,0.f};
  short8 na0, na1, na2, na3;
#pragma unroll
  for (int c = 0; c < 8; ++c) {
    const int k0 = c * 4;
    if (c < 7) {
      na0 = LDA(k0 + 4); na1 = LDA(k0 + 5); na2 = LDA(k0 + 6); na3 = LDA(k0 + 7);
    }
#pragma unroll
    for (int j = 0; j < 4; ++j) {
      const int kk = k0 + j;
      short8 a = (j == 0) ? ca0 : (j == 1) ? ca1 : (j == 2) ? ca2 : ca3;
      short8 w0 = *reinterpret_cast<const short8*>(WL + kk * 1024);
      short8 w1 = *reinterpret_cast<const short8*>(WL + 32768 + kk * 1024);
      short8 w2 = *reinterpret_cast<const short8*>(WL + 65536 + kk * 1024);
      short8 w3 = *reinterpret_cast<const short8*>(WL + 98304 + kk * 1024);
      ac0 = MFMA16(a, w0, ac0, 0, 0, 0);
      ac1 = MFMA16(a, w1, ac1, 0, 0, 0);
      ac2 = MFMA16(a, w2, ac2, 0, 0, 0);
      ac3 = MFMA16(a, w3, ac3, 0, 0, 0);
    }
    ca0 = na0; ca1 = na1; ca2 = na2; ca3 = na3;
  }

  u16* stg = reinterpret_cast<u16*>(smem + 131072);
#pragma unroll
  for (int e = 0; e < 4; ++e) {
    float zi = ac0[e] + bg0, zj = ac1[e] + bg1, zf = ac2[e] + bg2, zo = ac3[e] + bg3;
    float cprev = cpre[e];
    float cn = cprev * sigm(zf + 1.0f) + sigm(zi) * tanhe(zj);
    float hn = tanhe(cn) * sigm(zo);
    bool valid = tcur < sl[e];
    union { float f; u32 u; } hp; hp.u = ((u32)hp16[e]) << 16;
    float hkeep = valid ? hn : hp.f;
    cme[e] = valid ? cn : cprev;
    stg[rf * 256 + (((lane & 15) >> 3) * 16 + (lane >> 4) * 4 + e) * 8 + (lane & 7)] = f2bf(hkeep);
    if (role) {
      union { float f; u32 u; } hv; hv.u = ((u32)h0nraw[e]) << 16;
      out[((size_t)(rowB + e) * Tn + tcur) * Dn + d0] = valid ? (hn + hv.f) : 0.0f;
    }
  }
  __syncthreads();
  {
    const int rft = tid >> 6, u = tid & 63;
    u64 v = reinterpret_cast<const u64*>(stg)[tid];
    u64* hw8 = reinterpret_cast<u64*>(hfSelf + (size_t)Wp * 131072);
    size_t o8 = (size_t)((mtile * 4 + rft) * 16 + kkd) * 128 + ((dsl & 1) * 32 + (u >> 1)) * 2 + (u & 1);
    hw8[o8] = v;
  }
}

extern "C" void kernel_launch(void* const* d_in, const int* in_sizes, int n_in,
                              void* d_out, int out_size, void* d_ws, size_t ws_size,
                              hipStream_t stream) {
  (void)in_sizes; (void)n_in; (void)out_size; (void)ws_size;
  const float* x  = (const float*)d_in[0];
  const int* seq  = (const int*)d_in[1];
  const float* W0 = (const float*)d_in[2];
  const float* b0 = (const float*)d_in[3];
  const float* W1 = (const float*)d_in[4];
  const float* b1 = (const float*)d_in[5];
  float* out = (float*)d_out;

  char* ws = (char*)d_ws;
  // ws layout (bytes):
  //   xf   : 0          .. 52,428,800   bf16 fragment-major x
  //   Wf   : 52,428,800 .. 60,817,408   bf16 fragment-major weights
  //   hf0  : 60,817,408 .. 61,341,696   bf16 frag h0 [2 parities]
  //   hf1  : 61,341,696 .. 61,865,984   bf16 frag h1 [2 parities]
  //   bar  : 61,865,984 ..              u32 barrier counters (4 mtile groups, 256B apart)
  //          (same region doubles as cbuf for the fallback path)
  u16*  xf   = (u16*)(ws);
  u16*  Wf   = (u16*)(ws + 52428800);
  u16*  hf0  = (u16*)(ws + 60817408);
  u16*  hf1  = (u16*)(ws + 61341696);
  u32*  bar  = (u32*)(ws + 61865984);
  float* cbuf = (float*)(ws + 61865984);

  hipMemsetAsync(ws + 60817408, 0, 2097152, stream);  // h frags (both parities) + counters
  hipLaunchKernelGGL(cvt_x_frag, dim3(12800), dim3(256), 0, stream, x, xf);
  hipLaunchKernelGGL(cvt_w_frag, dim3(1024), dim3(256), 0, stream, W0, W1, Wf);

  hipFuncSetAttribute((const void*)rnn_persist,
                      hipFuncAttributeMaxDynamicSharedMemorySize, 133120);
  hipFuncSetAttribute((const void*)rnn_step,
                      hipFuncAttributeMaxDynamicSharedMemorySize, 133120);

  void* args[] = { (void*)&xf, (void*)&Wf, (void*)&b0, (void*)&b1, (void*)&seq,
                   (void*)&hf0, (void*)&hf1, (void*)&bar, (void*)&out };
  hipError_t err = hipLaunchCooperativeKernel((void*)rnn_persist, dim3(256), dim3(256),
                                              args, 133120, stream);
  if (err != hipSuccess) {
    // fallback: proven multi-launch skewed pipeline
    for (int p = 0; p <= Tn; ++p) {
      hipLaunchKernelGGL(rnn_step, dim3(256), dim3(256), 133120, stream,
                         xf, Wf, b0, b1, seq, hf0, hf1, cbuf, out, p);
    }
  }
}

// Round 2
// 1203.112 us; speedup vs baseline: 4.1499x; 4.1499x over previous
//
#include <hip/hip_runtime.h>

using short8 = __attribute__((ext_vector_type(8))) short;
using f32x4  = __attribute__((ext_vector_type(4))) float;
typedef unsigned short u16;
typedef unsigned int   u32;
typedef unsigned long long u64;

constexpr int Bn = 256;   // batch
constexpr int Tn = 200;   // time steps
constexpr int Dn = 512;   // hidden size

__device__ __forceinline__ u16 f2bf(float x) {
  union { float f; unsigned u; } v; v.f = x;
  unsigned r = v.u + 0x7FFFu + ((v.u >> 16) & 1u);  // RNE
  return (u16)(r >> 16);
}
__device__ __forceinline__ float sigm(float x) { return 1.0f / (1.0f + __expf(-x)); }
__device__ __forceinline__ float tanhe(float x) { return 1.0f - 2.0f / (__expf(2.0f * x) + 1.0f); }

// ---------- prep: x f32 [B][T][D] -> xf fragment-major bf16 [mtile4][t200][rf4][kkd16][lane64][8] ----------
__global__ void cvt_x_frag(const float* __restrict__ x, u16* __restrict__ xf) {
  int i = blockIdx.x * 256 + threadIdx.x;          // exactly 3,276,800 lane-tasks
  int lane = i & 63;
  int kkd  = (i >> 6) & 15;
  int rf   = (i >> 10) & 3;
  int mt_t = i >> 12;                              // mtile*200 + t
  int t = mt_t % 200, mtile = mt_t / 200;
  int row = mtile * 64 + rf * 16 + (lane & 15);
  int k0  = kkd * 32 + (lane >> 4) * 8;
  const float* s = x + ((size_t)row * Tn + t) * Dn + k0;
  float4 v0 = *reinterpret_cast<const float4*>(s);
  float4 v1 = *reinterpret_cast<const float4*>(s + 4);
  short8 r;
  r[0]=(short)f2bf(v0.x); r[1]=(short)f2bf(v0.y); r[2]=(short)f2bf(v0.z); r[3]=(short)f2bf(v0.w);
  r[4]=(short)f2bf(v1.x); r[5]=(short)f2bf(v1.y); r[6]=(short)f2bf(v1.z); r[7]=(short)f2bf(v1.w);
  reinterpret_cast<short8*>(xf)[i] = r;
}

// ---------- prep: W [1024][2048] f32 -> Wf fragment-major bf16 [role2][dsl32][g4][kk32][lane64][8] ----------
__global__ void cvt_w_frag(const float* __restrict__ W0, const float* __restrict__ W1,
                           u16* __restrict__ Wf) {
  __shared__ u16 T[64][65];                        // [k][n] tile, padded
  int b = blockIdx.x;                              // 1024 blocks: role(2) x kt(16) x nt(32)
  int nt = b & 31, kt = (b >> 5) & 15, role = b >> 9;
  const float* W = role ? W1 : W0;
  int t = threadIdx.x;
  int k0 = kt * 64, n0 = nt * 64;
  int kr = t >> 6, nl = t & 63;
#pragma unroll
  for (int r = 0; r < 16; ++r) {
    int k = r * 4 + kr;
    T[k][nl] = f2bf(W[(size_t)(k0 + k) * 2048 + n0 + nl]);   // coalesced over n
  }
  __syncthreads();
  int g = n0 >> 9;
  int dslBase = (n0 & 511) >> 4;
  int kkBase  = k0 >> 5;
  int lane = t & 63, grp = t >> 6;
  int lr = lane & 15, lk = lane >> 4;
#pragma unroll
  for (int c = grp; c < 8; c += 4) {
    int dslL = c & 3, kkL = c >> 2;
    int dsl = dslBase + dslL, kk = kkBase + kkL;
    short8 v;
#pragma unroll
    for (int e = 0; e < 8; ++e)
      v[e] = (short)T[kkL * 32 + lk * 8 + e][dslL * 16 + lr];
    *reinterpret_cast<short8*>(Wf + ((((size_t)(role * 32 + dsl) * 4 + g) * 32 + kk) * 64 + lane) * 8) = v;
  }
}

#define MFMA16 __builtin_amdgcn_mfma_f32_16x16x32_bf16
#define GLOAD_LDS(g, l) __builtin_amdgcn_global_load_lds(                    \
    (const __attribute__((address_space(1))) void*)(g),                      \
    (__attribute__((address_space(3))) void*)(l), 16, 0, 0)

// coherent (LLC point-of-coherence) 4x16B load batch: bypasses L1+L2 via sc0 sc1
#define ISS4C(A0, A1, A2, A3, P)                                             \
  asm volatile("global_load_dwordx4 %0, %4, off sc0 sc1\n\t"                 \
               "global_load_dwordx4 %1, %4, off offset:1024 sc0 sc1\n\t"     \
               "global_load_dwordx4 %2, %4, off offset:2048 sc0 sc1\n\t"     \
               "global_load_dwordx4 %3, %4, off offset:3072 sc0 sc1"         \
               : "=v"(A0), "=v"(A1), "=v"(A2), "=v"(A3) : "v"(P) : "memory")
// normal cached 4x16B load batch (iteration-private x data)
#define ISS4N(A0, A1, A2, A3, P)                                             \
  asm volatile("global_load_dwordx4 %0, %4, off\n\t"                         \
               "global_load_dwordx4 %1, %4, off offset:1024\n\t"             \
               "global_load_dwordx4 %2, %4, off offset:2048\n\t"             \
               "global_load_dwordx4 %3, %4, off offset:3072"                 \
               : "=v"(A0), "=v"(A1), "=v"(A2), "=v"(A3) : "v"(P) : "memory")
// counted wait + scheduling fence (rule: MFMA must not hoist above the wait)
#define WAITV(N)                                                             \
  asm volatile("s_waitcnt vmcnt(" #N ")" ::: "memory");                      \
  __builtin_amdgcn_sched_barrier(0)
#define MMK(av, kk) {                                                        \
    short8 w0 = *reinterpret_cast<const short8*>(WL + (kk) * 1024);          \
    short8 w1 = *reinterpret_cast<const short8*>(WL + 32768 + (kk) * 1024);  \
    short8 w2 = *reinterpret_cast<const short8*>(WL + 65536 + (kk) * 1024);  \
    short8 w3 = *reinterpret_cast<const short8*>(WL + 98304 + (kk) * 1024);  \
    ac0 = MFMA16(av, w0, ac0, 0, 0, 0);                                      \
    ac1 = MFMA16(av, w1, ac1, 0, 0, 0);                                      \
    ac2 = MFMA16(av, w2, ac2, 0, 0, 0);                                      \
    ac3 = MFMA16(av, w3, ac3, 0, 0, 0); }

// ---------- persistent cooperative kernel: entire 200-step scan in ONE launch ----------
// 256 blocks x 256 threads, 1 block/CU. q=blk&7: role=q&1, mtile=q>>1 (XCD-grouped), dsl=blk>>3.
// W staged into LDS ONCE. Cross-block h traffic entirely via sc0/sc1 LLC-coherent accesses:
// NO fences, NO wbl2/inv, NO atomic RMW. Barrier = per-block flag store + 64-lane poll.
// A-operands: 36 loads issued up-front, consumed with hand-counted vmcnt (8 batches).
extern "C" __global__ void __launch_bounds__(256, 1)
rnn_persist(const u16* __restrict__ xf, const u16* __restrict__ Wf,
            const float* __restrict__ b0, const float* __restrict__ b1,
            const int* __restrict__ seq,
            u16* __restrict__ hf0, u16* __restrict__ hf1,
            u32* __restrict__ bar, float* __restrict__ out) {
  extern __shared__ __align__(16) char smem[];
  const int blk = blockIdx.x;
  const int q = blk & 7;
  const int role = q & 1;
  const int mtile = q >> 1;
  const int dsl = blk >> 3;
  const int tid = threadIdx.x;
  const int rf = tid >> 6, lane = tid & 63;

  // ---- one-time W staging: 32 direct global->LDS 16B ops per thread ----
  {
    const char* gsrc = reinterpret_cast<const char*>(Wf)
                     + (size_t)(role * 32 + dsl) * 131072 + tid * 16;
    char* lds = smem + tid * 16;
#pragma unroll
    for (int i = 0; i < 32; ++i)
      GLOAD_LDS(gsrc + i * 4096, lds + i * 4096);
  }

  const char* xfb = reinterpret_cast<const char*>(xf);
  const char* h0b = reinterpret_cast<const char*>(hf0);
  const char* h1b = reinterpret_cast<const char*>(hf1);
  const int aoff = rf * 16384 + lane * 16;
  const char* WL = smem + lane * 16;               // + g*32768 + kk*1024 (ds_read_b128)

  const int d0 = dsl * 16 + (lane & 15);
  const float* bias = role ? b1 : b0;
  const float bg0 = bias[d0], bg1 = bias[512 + d0], bg2 = bias[1024 + d0], bg3 = bias[1536 + d0];
  const int rowB = mtile * 64 + rf * 16 + (lane >> 4) * 4;
  int sl[4];
#pragma unroll
  for (int e = 0; e < 4; ++e) sl[e] = seq[rowB + e];

  // fragment-layout u16 offset of this thread's (rowB+e, d0) values in h buffers
  const int kkd = dsl >> 1;
  const int lane_t_base = ((((dsl & 1) << 1) | ((lane & 15) >> 3)) << 4) + (lane >> 4) * 4;
  const size_t hoff0 = (size_t)mtile * 32768 + (size_t)(rf * 16 + kkd) * 512
                     + (size_t)lane_t_base * 8 + (lane & 7);

  u16* hfSelf = role ? hf1 : hf0;
  u16* stg = reinterpret_cast<u16*>(smem + 131072);
  const int uu = tid & 63;
  const size_t o8 = (size_t)((mtile * 4 + rf) * 16 + kkd) * 128
                  + ((dsl & 1) * 32 + (uu >> 1)) * 2 + (uu & 1);
  u32* flagme = bar + mtile * 64 + role * 32 + dsl;
  const u32* fb = bar + mtile * 64 + tid;          // poll address (tid<64 only)

  float creg[4]  = {0.f, 0.f, 0.f, 0.f};           // c-state in registers
  float hkeep[4] = {0.f, 0.f, 0.f, 0.f};           // copy-through h in registers

  __syncthreads();                                 // W resident in LDS from here on

#pragma unroll 1
  for (int p = 0; p <= Tn; ++p) {
    const bool act = role ? (p >= 1) : (p < Tn);
    const int Rp = (p & 1) ^ 1, Wp = p & 1;
    if (act) {
      const int tcur = role ? (p - 1) : p;
      const size_t hRp = (size_t)Rp * 262144 + (size_t)mtile * 65536;
      const char* Alo = (role == 0)
          ? xfb + ((size_t)mtile * Tn + p) * 65536 + aoff
          : h0b + hRp + aoff;
      const char* Ahi = (role == 0) ? h0b + hRp + aoff : h1b + hRp + aoff;

      // residual h0n (role1 consumes; role0 issues harmlessly for uniform vmcnt counting)
      const char* hra = reinterpret_cast<const char*>(
          reinterpret_cast<const u16*>(h0b) + (size_t)Rp * 131072 + hoff0);
      u32 hn0, hn1, hn2, hn3;
      asm volatile("global_load_ushort %0, %4, off sc0 sc1\n\t"
                   "global_load_ushort %1, %4, off offset:16 sc0 sc1\n\t"
                   "global_load_ushort %2, %4, off offset:32 sc0 sc1\n\t"
                   "global_load_ushort %3, %4, off offset:48 sc0 sc1"
                   : "=v"(hn0), "=v"(hn1), "=v"(hn2), "=v"(hn3) : "v"(hra) : "memory");

      short8 A0,A1,A2,A3,A4,A5,A6,A7,A8,A9,A10,A11,A12,A13,A14,A15;
      short8 B0,B1,B2,B3,B4,B5,B6,B7,B8,B9,B10,B11,B12,B13,B14,B15;
      if (role == 0) {                             // x: normal cached (L2-shared on XCD)
        ISS4N(A0,A1,A2,A3,    Alo);
        ISS4N(A4,A5,A6,A7,    Alo + 4096);
        ISS4N(A8,A9,A10,A11,  Alo + 8192);
        ISS4N(A12,A13,A14,A15,Alo + 12288);
      } else {                                     // h0: LLC-coherent
        ISS4C(A0,A1,A2,A3,    Alo);
        ISS4C(A4,A5,A6,A7,    Alo + 4096);
        ISS4C(A8,A9,A10,A11,  Alo + 8192);
        ISS4C(A12,A13,A14,A15,Alo + 12288);
      }
      ISS4C(B0,B1,B2,B3,    Ahi);                  // h: LLC-coherent
      ISS4C(B4,B5,B6,B7,    Ahi + 4096);
      ISS4C(B8,B9,B10,B11,  Ahi + 8192);
      ISS4C(B12,B13,B14,B15,Ahi + 12288);

      f32x4 ac0 = {0.f,0.f,0.f,0.f}, ac1 = {0.f,0.f,0.f,0.f};
      f32x4 ac2 = {0.f,0.f,0.f,0.f}, ac3 = {0.f,0.f,0.f,0.f};

      // 36 loads outstanding; consume batch c once first 8+4c are done
      WAITV(28); MMK(A0,0)  MMK(A1,1)  MMK(A2,2)  MMK(A3,3)
      WAITV(24); MMK(A4,4)  MMK(A5,5)  MMK(A6,6)  MMK(A7,7)
      WAITV(20); MMK(A8,8)  MMK(A9,9)  MMK(A10,10) MMK(A11,11)
      WAITV(16); MMK(A12,12) MMK(A13,13) MMK(A14,14) MMK(A15,15)
      WAITV(12); MMK(B0,16) MMK(B1,17) MMK(B2,18) MMK(B3,19)
      WAITV(8);  MMK(B4,20) MMK(B5,21) MMK(B6,22) MMK(B7,23)
      WAITV(4);  MMK(B8,24) MMK(B9,25) MMK(B10,26) MMK(B11,27)
      WAITV(0);  MMK(B12,28) MMK(B13,29) MMK(B14,30) MMK(B15,31)

      // epilogue: gates (i,j,f,o), state update from registers, copy-through from registers
      const u32 hnv[4] = {hn0, hn1, hn2, hn3};
#pragma unroll
      for (int e = 0; e < 4; ++e) {
        float zi = ac0[e] + bg0, zj = ac1[e] + bg1, zf = ac2[e] + bg2, zo = ac3[e] + bg3;
        float cprev = creg[e];
        float cn = cprev * sigm(zf + 1.0f) + sigm(zi) * tanhe(zj);
        float hn = tanhe(cn) * sigm(zo);
        bool valid = tcur < sl[e];
        float hk = valid ? hn : hkeep[e];
        creg[e] = valid ? cn : cprev;
        hkeep[e] = hk;
        stg[rf * 256 + (((lane & 15) >> 3) * 16 + (lane >> 4) * 4 + e) * 8 + (lane & 7)] = f2bf(hk);
        if (role) {
          union { float f; u32 u; } hv; hv.u = hnv[e] << 16;               // h0n (bf16)
          out[((size_t)(rowB + e) * Tn + tcur) * Dn + d0] = valid ? (hn + hv.f) : 0.0f;
        }
      }
      __syncthreads();
      {  // coalesced LLC-coherent store of the 2KB h slice into the write parity
        u64 v = reinterpret_cast<const u64*>(stg)[tid];
        u64* ha = reinterpret_cast<u64*>(hfSelf + (size_t)Wp * 131072) + o8;
        asm volatile("global_store_dwordx2 %0, %1, off sc0 sc1" :: "v"(ha), "v"(v) : "memory");
      }
      asm volatile("s_waitcnt vmcnt(0)" ::: "memory");   // h (and out) at point of coherence
    }

    if (p == Tn) break;                            // nothing reads after the last step

    // ---- per-mtile 64-block barrier: per-block flag store + one-wave poll ----
    __syncthreads();                               // all waves of this block drained
    if (tid == 0) {
      u32 tv = (u32)(p + 1);
      asm volatile("global_store_dword %0, %1, off sc0 sc1" :: "v"(flagme), "v"(tv) : "memory");
    }
    if (tid < 64) {                                // wave 0: lane l watches flag l
      const int tgt = p + 1;
      u32 fv;
      do {
        asm volatile("global_load_dword %0, %1, off sc0 sc1\n\t"
                     "s_waitcnt vmcnt(0)"
                     : "=v"(fv) : "v"(fb) : "memory");
      } while (!__all((int)fv >= tgt));
    }
    __syncthreads();
  }
}

// ---------- fallback per-step kernel (only used if cooperative launch is rejected) ----------
#define LDA(kk) (*reinterpret_cast<const short8*>(                           \
    (kk) < 16 ? (Alo + (size_t)(kk) * 1024) : (Ahi + (size_t)((kk) - 16) * 1024)))

extern "C" __global__ void __launch_bounds__(256, 1)
rnn_step(const u16* __restrict__ xf, const u16* __restrict__ Wf,
         const float* __restrict__ b0, const float* __restrict__ b1,
         const int* __restrict__ seq,
         u16* __restrict__ hf0, u16* __restrict__ hf1,
         float* __restrict__ cbuf, float* __restrict__ out, int p) {
  extern __shared__ __align__(16) char smem[];
  const int blk = blockIdx.x;
  const int role = blk & 1;
  const int mtile = (blk >> 1) & 3;
  const int dsl = blk >> 3;
  const bool act = role ? (p >= 1) : (p < Tn);
  if (!act) return;

  const int tid = threadIdx.x;
  const int rf = tid >> 6, lane = tid & 63;
  const int Rp = (p & 1) ^ 1, Wp = p & 1;
  const int tcur = role ? (p - 1) : p;

  {
    const char* gsrc = reinterpret_cast<const char*>(Wf)
                     + (size_t)(role * 32 + dsl) * 131072 + tid * 16;
    char* lds = smem + tid * 16;
#pragma unroll
    for (int i = 0; i < 32; ++i)
      GLOAD_LDS(gsrc + i * 4096, lds + i * 4096);
  }

  const char* h0base = reinterpret_cast<const char*>(hf0);
  const char* h1base = reinterpret_cast<const char*>(hf1);
  const size_t hRp = (size_t)Rp * 262144 + (size_t)mtile * 65536;
  const int aoff = rf * 16384 + lane * 16;

  const char* Alo;
  const char* Ahi;
  if (role == 0) {
    Alo = reinterpret_cast<const char*>(xf) + ((size_t)mtile * Tn + p) * 65536 + aoff;
    Ahi = h0base + hRp + aoff;
  } else {
    Alo = h0base + hRp + aoff;
    Ahi = h1base + hRp + aoff;
  }
  const char* WL = smem + lane * 16;

  short8 ca0 = LDA(0), ca1 = LDA(1), ca2 = LDA(2), ca3 = LDA(3);

  const int d0 = dsl * 16 + (lane & 15);
  const float* bias = role ? b1 : b0;
  const float bg0 = bias[d0], bg1 = bias[512 + d0], bg2 = bias[1024 + d0], bg3 = bias[1536 + d0];
  const int rowB = mtile * 64 + rf * 16 + (lane >> 4) * 4;
  int sl[4];
#pragma unroll
  for (int e = 0; e < 4; ++e) sl[e] = seq[rowB + e];

  const int kkd = dsl >> 1;
  const int lane_t_base = ((((dsl & 1) << 1) | ((lane & 15) >> 3)) << 4) + (lane >> 4) * 4;
  const size_t hoff0 = (size_t)mtile * 32768 + (size_t)(rf * 16 + kkd) * 512
                     + (size_t)lane_t_base * 8 + (lane & 7);

  u16 h0nraw[4];
  if (role) {
    const u16* hr = reinterpret_cast<const u16*>(h0base) + (size_t)Rp * 131072;
#pragma unroll
    for (int e = 0; e < 4; ++e) h0nraw[e] = hr[hoff0 + e * 8];
  }
  float* cme = cbuf + ((size_t)blk * 256 + tid) * 4;
  float cpre[4];
#pragma unroll
  for (int e = 0; e < 4; ++e) cpre[e] = cme[e];
  u16* hfSelf = role ? hf1 : hf0;
  const u16* hprev = hfSelf + (size_t)Rp * 131072;
  u16 hp16[4];
#pragma unroll
  for (int e = 0; e < 4; ++e) hp16[e] = hprev[hoff0 + e * 8];

  __syncthreads();

  f32x4 ac0 = {0.f,0.f,0.f,0.f}, ac1 = {0.f,0.f,0.f,0.f};
  f32x4 ac2 = {0.f,0.f,0.f,0.f}, ac3 = {0.f,0.f,0.f,0.f};
  short8 na0, na1, na2, na3;
#pragma unroll
  for (int c = 0; c < 8; ++c) {
    const int k0 = c * 4;
    if (c < 7) {
      na0 = LDA(k0 + 4); na1 = LDA(k0 + 5); na2 = LDA(k0 + 6); na3 = LDA(k0 + 7);
    }
#pragma unroll
    for (int j = 0; j < 4; ++j) {
      const int kk = k0 + j;
      short8 a = (j == 0) ? ca0 : (j == 1) ? ca1 : (j == 2) ? ca2 : ca3;
      short8 w0 = *reinterpret_cast<const short8*>(WL + kk * 1024);
      short8 w1 = *reinterpret_cast<const short8*>(WL + 32768 + kk * 1024);
      short8 w2 = *reinterpret_cast<const short8*>(WL + 65536 + kk * 1024);
      short8 w3 = *reinterpret_cast<const short8*>(WL + 98304 + kk * 1024);
      ac0 = MFMA16(a, w0, ac0, 0, 0, 0);
      ac1 = MFMA16(a, w1, ac1, 0, 0, 0);
      ac2 = MFMA16(a, w2, ac2, 0, 0, 0);
      ac3 = MFMA16(a, w3, ac3, 0, 0, 0);
    }
    ca0 = na0; ca1 = na1; ca2 = na2; ca3 = na3;
  }

  u16* stg = reinterpret_cast<u16*>(smem + 131072);
#pragma unroll
  for (int e = 0; e < 4; ++e) {
    float zi = ac0[e] + bg0, zj = ac1[e] + bg1, zf = ac2[e] + bg2, zo = ac3[e] + bg3;
    float cprev = cpre[e];
    float cn = cprev * sigm(zf + 1.0f) + sigm(zi) * tanhe(zj);
    float hn = tanhe(cn) * sigm(zo);
    bool valid = tcur < sl[e];
    union { float f; u32 u; } hp; hp.u = ((u32)hp16[e]) << 16;
    float hkeep = valid ? hn : hp.f;
    cme[e] = valid ? cn : cprev;
    stg[rf * 256 + (((lane & 15) >> 3) * 16 + (lane >> 4) * 4 + e) * 8 + (lane & 7)] = f2bf(hkeep);
    if (role) {
      union { float f; u32 u; } hv; hv.u = ((u32)h0nraw[e]) << 16;
      out[((size_t)(rowB + e) * Tn + tcur) * Dn + d0] = valid ? (hn + hv.f) : 0.0f;
    }
  }
  __syncthreads();
  {
    const int rft = tid >> 6, u = tid & 63;
    u64 v = reinterpret_cast<const u64*>(stg)[tid];
    u64* hw8 = reinterpret_cast<u64*>(hfSelf + (size_t)Wp * 131072);
    size_t o8 = (size_t)((mtile * 4 + rft) * 16 + kkd) * 128 + ((dsl & 1) * 32 + (u >> 1)) * 2 + (u & 1);
    hw8[o8] = v;
  }
}

extern "C" void kernel_launch(void* const* d_in, const int* in_sizes, int n_in,
                              void* d_out, int out_size, void* d_ws, size_t ws_size,
                              hipStream_t stream) {
  (void)in_sizes; (void)n_in; (void)out_size; (void)ws_size;
  const float* x  = (const float*)d_in[0];
  const int* seq  = (const int*)d_in[1];
  const float* W0 = (const float*)d_in[2];
  const float* b0 = (const float*)d_in[3];
  const float* W1 = (const float*)d_in[4];
  const float* b1 = (const float*)d_in[5];
  float* out = (float*)d_out;

  char* ws = (char*)d_ws;
  // ws layout (bytes):
  //   xf   : 0          .. 52,428,800   bf16 fragment-major x
  //   Wf   : 52,428,800 .. 60,817,408   bf16 fragment-major weights
  //   hf0  : 60,817,408 .. 61,341,696   bf16 frag h0 [2 parities]
  //   hf1  : 61,341,696 .. 61,865,984   bf16 frag h1 [2 parities]
  //   bar  : 61,865,984 ..              u32 flags (4 mtiles x 64 blocks)
  //          (same region doubles as cbuf for the fallback path)
  u16*  xf   = (u16*)(ws);
  u16*  Wf   = (u16*)(ws + 52428800);
  u16*  hf0  = (u16*)(ws + 60817408);
  u16*  hf1  = (u16*)(ws + 61341696);
  u32*  bar  = (u32*)(ws + 61865984);
  float* cbuf = (float*)(ws + 61865984);

  hipMemsetAsync(ws + 60817408, 0, 2097152, stream);  // h frags (both parities) + flags
  hipLaunchKernelGGL(cvt_x_frag, dim3(12800), dim3(256), 0, stream, x, xf);
  hipLaunchKernelGGL(cvt_w_frag, dim3(1024), dim3(256), 0, stream, W0, W1, Wf);

  hipFuncSetAttribute((const void*)rnn_persist,
                      hipFuncAttributeMaxDynamicSharedMemorySize, 133120);
  hipFuncSetAttribute((const void*)rnn_step,
                      hipFuncAttributeMaxDynamicSharedMemorySize, 133120);

  void* args[] = { (void*)&xf, (void*)&Wf, (void*)&b0, (void*)&b1, (void*)&seq,
                   (void*)&hf0, (void*)&hf1, (void*)&bar, (void*)&out };
  hipError_t err = hipLaunchCooperativeKernel((void*)rnn_persist, dim3(256), dim3(256),
                                              args, 133120, stream);
  if (err != hipSuccess) {
    // fallback: proven multi-launch skewed pipeline
    for (int p = 0; p <= Tn; ++p) {
      hipLaunchKernelGGL(rnn_step, dim3(256), dim3(256), 133120, stream,
                         xf, Wf, b0, b1, seq, hf0, hf1, cbuf, out, p);
    }
  }
}